// Round 2
// baseline (3358.656 us; speedup 1.0000x reference)
//
#include <hip/hip_runtime.h>
#include <hip/hip_bf16.h>
#include <cmath>

#define DEVI __device__ __forceinline__

constexpr int Hn   = 2048;   // hidden
constexpr int In   = 1408;   // per-expert intermediate
constexpr int En   = 16;     // routed experts
constexpr int Kn   = 4;      // top-k
constexpr int ISHn = 2816;   // shared intermediate
constexpr int Tn   = 8192;   // tokens (B*S)
constexpr int Rn   = Tn * Kn; // total routed rows = 32768

typedef __attribute__((ext_vector_type(4))) float f32x4;
typedef __attribute__((ext_vector_type(8))) __bf16 bf16x8;
typedef __attribute__((ext_vector_type(8))) unsigned short u16x8;

DEVI unsigned short f2bf(float f) {
  unsigned int u = __builtin_bit_cast(unsigned int, f);
  unsigned int r = (u + 0x7fffu + ((u >> 16) & 1u)) >> 16;
  return (unsigned short)r;
}
DEVI float bf2f(unsigned short h) {
  return __builtin_bit_cast(float, (unsigned int)h << 16);
}

DEVI f32x4 mfma16(bf16x8 a, bf16x8 b, f32x4 c) {
  return __builtin_amdgcn_mfma_f32_16x16x32_bf16(a, b, c, 0, 0, 0);
}

DEVI bf16x8 lds_frag(const unsigned short* p) {
  return __builtin_bit_cast(bf16x8, *reinterpret_cast<const u16x8*>(p));
}

DEVI void gload_lds16(const void* src, void* dst) {
  __builtin_amdgcn_global_load_lds(
      (const __attribute__((address_space(1))) void*)src,
      (__attribute__((address_space(3))) void*)dst, 16, 0, 0);
}

DEVI void pack8(unsigned short* dst, float4 a, float4 b) {
  u16x8 v;
  v[0] = f2bf(a.x); v[1] = f2bf(a.y); v[2] = f2bf(a.z); v[3] = f2bf(a.w);
  v[4] = f2bf(b.x); v[5] = f2bf(b.y); v[6] = f2bf(b.z); v[7] = f2bf(b.w);
  *reinterpret_cast<u16x8*>(dst) = v;
}

// ---------------- x -> bf16 ----------------
__global__ void cvt_x(const float* __restrict__ x, unsigned short* __restrict__ xb) {
  constexpr int Nv = Tn * Hn / 4;
  int stride = gridDim.x * blockDim.x;
  for (int v = blockIdx.x * blockDim.x + threadIdx.x; v < Nv; v += stride) {
    float4 a = reinterpret_cast<const float4*>(x)[v];
    ushort4 o;
    o.x = f2bf(a.x); o.y = f2bf(a.y); o.z = f2bf(a.z); o.w = f2bf(a.w);
    reinterpret_cast<ushort4*>(xb)[v] = o;
  }
}

// ---------------- zero counts + cursor ----------------
__global__ void zero_k(int* p) { p[threadIdx.x] = 0; }

// ---------------- router: one wave per token, fp64 scoring ----------------
__global__ __launch_bounds__(256)
void router_k(const float* __restrict__ x, const float* __restrict__ rg,
              const float* __restrict__ ru, const float* __restrict__ esc,
              const float* __restrict__ ebi, int* __restrict__ counts,
              int* __restrict__ topk, float* __restrict__ wval) {
  int w = (blockIdx.x * blockDim.x + threadIdx.x) >> 6;
  int lane = threadIdx.x & 63;
  if (w >= Tn) return;
  const float* xr = x + (size_t)w * Hn;
  float xv[Hn / 64];
#pragma unroll
  for (int j = 0; j < Hn / 64; ++j) xv[j] = xr[lane + j * 64];

  double pr[En];
  double mx = -1e300;
#pragma unroll
  for (int e = 0; e < En; ++e) {
    const float* gr = rg + (size_t)e * Hn;
    const float* ur = ru + (size_t)e * Hn;
    double pg = 0.0, pu = 0.0;
#pragma unroll
    for (int j = 0; j < Hn / 64; ++j) {
      pg += (double)xv[j] * (double)gr[lane + j * 64];
      pu += (double)xv[j] * (double)ur[lane + j * 64];
    }
#pragma unroll
    for (int s = 32; s > 0; s >>= 1) {
      pg += __shfl_xor(pg, s);
      pu += __shfl_xor(pu, s);
    }
    double sg = pg / (1.0 + exp(-pg));     // silu
    double sc = fabs(pu * sg);
    pr[e] = sc;
    mx = fmax(mx, sc);
  }
  double den = 0.0;
#pragma unroll
  for (int e = 0; e < En; ++e) { pr[e] = exp(pr[e] - mx); den += pr[e]; }

  if (lane == 0) {
    double invden = 1.0 / den;
    unsigned chosen = 0;
    for (int k = 0; k < Kn; ++k) {
      double bv = -1e300; int best = 0;
#pragma unroll
      for (int e = 0; e < En; ++e) {
        double be = pr[e] * invden + (double)ebi[e];
        if (!((chosen >> e) & 1u) && be > bv) { bv = be; best = e; }
      }
      chosen |= 1u << best;
      topk[w * Kn + k] = best;
      double pbest = bv - (double)ebi[best];
      wval[w * Kn + k] = (float)(1.0 + pbest * (double)esc[best]);
      atomicAdd(&counts[best], 1);
    }
  }
}

// ---------------- prefix over expert counts ----------------
__global__ void prefix_k(const int* __restrict__ counts, int* __restrict__ off) {
  if (threadIdx.x == 0) {
    int a = 0;
    for (int e = 0; e < En; ++e) { off[e] = a; a += counts[e]; }
    off[En] = a;
  }
}

// ---------------- build per-expert token lists + token->row map ----------------
__global__ void build_k(const int* __restrict__ topk, const float* __restrict__ wval,
                        const int* __restrict__ off, int* __restrict__ cursor,
                        int* __restrict__ list, float* __restrict__ cw,
                        int* __restrict__ rowOf) {
  int t = blockIdx.x * blockDim.x + threadIdx.x;
  if (t >= Tn) return;
  for (int k = 0; k < Kn; ++k) {
    int e = topk[t * Kn + k];
    int pos = atomicAdd(&cursor[e], 1);
    int r = off[e] + pos;
    list[r] = t;
    cw[r] = wval[t * Kn + k];
    rowOf[t * Kn + k] = r;
  }
}

// ---------------- up-proj: h = silu(A@Wg^T) * (A@Wu^T), A gathered ----------------
template <bool SHARED>
__global__ __launch_bounds__(256, 2)
void up_k(const unsigned short* __restrict__ xb,
          const float* __restrict__ Wgp, const float* __restrict__ Wup,
          const int* __restrict__ list, const int* __restrict__ off,
          const int* __restrict__ counts,
          unsigned short* __restrict__ hbuf, int Ncols) {
  int cnt, offE;
  const float *wg, *wu;
  if constexpr (SHARED) {
    cnt = Tn; offE = 0; wg = Wgp; wu = Wup;
  } else {
    int e = blockIdx.z;
    cnt = counts[e];
    offE = off[e];
    wg = Wgp + (size_t)e * In * Hn;
    wu = Wup + (size_t)e * In * Hn;
  }
  int m0 = blockIdx.x * 128;
  if (m0 >= cnt) return;
  int n0 = blockIdx.y * 64;

  __shared__ alignas(16) unsigned short As[128 * 64];
  __shared__ alignas(16) unsigned short Bg[64 * 64];
  __shared__ alignas(16) unsigned short Bu[64 * 64];

  int tid = threadIdx.x;
  int lane = tid & 63;
  int wv = tid >> 6;
  int wm = wv >> 1, wn = wv & 1;

  // A staging: pre-swizzled GLOBAL source, linear LDS dest (rule #21)
  const unsigned short* gA[4];
#pragma unroll
  for (int i = 0; i < 4; ++i) {
    int idx = i * 256 + tid;
    int row = idx >> 3, ch = idx & 7;
    int sch = ch ^ (row & 7);
    int rc = m0 + row; rc = rc < cnt ? rc : cnt - 1;
    int tok;
    if constexpr (SHARED) tok = m0 + row;
    else tok = list[offE + rc];
    gA[i] = xb + (size_t)tok * Hn + sch * 8;
  }
  // B staging: swizzled ds_write addresses
  int brow = tid >> 2, bq = tid & 3;
  const float* wgp = wg + (size_t)(n0 + brow) * Hn + bq * 16;
  const float* wup = wu + (size_t)(n0 + brow) * Hn + bq * 16;
  int sw0 = ((bq * 2) ^ (brow & 7)) << 3;
  int sw1 = ((bq * 2 + 1) ^ (brow & 7)) << 3;
  unsigned short* bg0 = &Bg[brow * 64 + sw0];
  unsigned short* bg1 = &Bg[brow * 64 + sw1];
  unsigned short* bu0 = &Bu[brow * 64 + sw0];
  unsigned short* bu1 = &Bu[brow * 64 + sw1];

  f32x4 accg[4][2], accu[4][2];
#pragma unroll
  for (int m = 0; m < 4; ++m)
#pragma unroll
    for (int n = 0; n < 2; ++n) {
      accg[m][n] = f32x4{0.f, 0.f, 0.f, 0.f};
      accu[m][n] = f32x4{0.f, 0.f, 0.f, 0.f};
    }

  for (int kb = 0; kb < Hn / 64; ++kb) {
#pragma unroll
    for (int i = 0; i < 4; ++i)
      gload_lds16(gA[i] + kb * 64, &As[i * 2048 + wv * 512]);
    {
      const float4* s = reinterpret_cast<const float4*>(wgp + kb * 64);
      pack8(bg0, s[0], s[1]);
      pack8(bg1, s[2], s[3]);
      const float4* s2 = reinterpret_cast<const float4*>(wup + kb * 64);
      pack8(bu0, s2[0], s2[1]);
      pack8(bu1, s2[2], s2[3]);
    }
    __syncthreads();
#pragma unroll
    for (int kk = 0; kk < 2; ++kk) {
      // swizzled chunk offset: row&7 == lane&7 for all fragment rows
      int soff = (((kk * 4 + (lane >> 4)) ^ (lane & 7)) << 3);
      bf16x8 a[4], bg2[2], bu2[2];
#pragma unroll
      for (int m = 0; m < 4; ++m)
        a[m] = lds_frag(&As[(wm * 64 + m * 16 + (lane & 15)) * 64 + soff]);
#pragma unroll
      for (int n = 0; n < 2; ++n) {
        bg2[n] = lds_frag(&Bg[(wn * 32 + n * 16 + (lane & 15)) * 64 + soff]);
        bu2[n] = lds_frag(&Bu[(wn * 32 + n * 16 + (lane & 15)) * 64 + soff]);
      }
#pragma unroll
      for (int m = 0; m < 4; ++m)
#pragma unroll
        for (int n = 0; n < 2; ++n) {
          accg[m][n] = mfma16(a[m], bg2[n], accg[m][n]);
          accu[m][n] = mfma16(a[m], bu2[n], accu[m][n]);
        }
    }
    __syncthreads();
  }

#pragma unroll
  for (int m = 0; m < 4; ++m) {
#pragma unroll
    for (int j = 0; j < 4; ++j) {
      int r = wm * 64 + m * 16 + (lane >> 4) * 4 + j;
      if (m0 + r < cnt) {
#pragma unroll
        for (int n = 0; n < 2; ++n) {
          int col = n0 + wn * 32 + n * 16 + (lane & 15);
          float g = accg[m][n][j], u = accu[m][n][j];
          float h = (g / (1.f + __expf(-g))) * u;
          hbuf[(size_t)(offE + m0 + r) * Ncols + col] = f2bf(h);
        }
      }
    }
  }
}

// ---------------- down-proj: C = h @ Wd^T ----------------
// SHARED: plain f32 stores to out.  !SHARED && YB: bf16 stores to yb.
// !SHARED && !YB: f32 atomicAdd to out.
template <bool SHARED, bool YB>
__global__ __launch_bounds__(256, 2)
void down_k(const unsigned short* __restrict__ hbuf,
            const float* __restrict__ Wdp,
            const int* __restrict__ list, const int* __restrict__ off,
            const int* __restrict__ counts, const float* __restrict__ cw,
            float* __restrict__ out, unsigned short* __restrict__ yb, int Kdim) {
  int cnt, offE;
  const float* wd;
  if constexpr (SHARED) { cnt = Tn; offE = 0; wd = Wdp; }
  else {
    int e = blockIdx.z;
    cnt = counts[e]; offE = off[e];
    wd = Wdp + (size_t)e * Hn * In;
  }
  int m0 = blockIdx.x * 128;
  if (m0 >= cnt) return;
  int n0 = blockIdx.y * 128;

  __shared__ alignas(16) unsigned short As[128 * 64];
  __shared__ alignas(16) unsigned short Bs[128 * 64];

  int tid = threadIdx.x, lane = tid & 63, wv = tid >> 6;
  int wm = wv >> 1, wn = wv & 1;

  const unsigned short* gA[4];
#pragma unroll
  for (int i = 0; i < 4; ++i) {
    int idx = i * 256 + tid;
    int row = idx >> 3, ch = idx & 7;
    int sch = ch ^ (row & 7);
    gA[i] = hbuf + (size_t)(offE + m0 + row) * Kdim + sch * 8;
  }
  int brow = tid >> 1, bh = tid & 1;
  const float* wdp = wd + (size_t)(n0 + brow) * Kdim + bh * 32;
  unsigned short* bsw[4];
#pragma unroll
  for (int q = 0; q < 4; ++q)
    bsw[q] = &Bs[brow * 64 + (((bh * 4 + q) ^ (brow & 7)) << 3)];

  f32x4 acc[4][4];
#pragma unroll
  for (int m = 0; m < 4; ++m)
#pragma unroll
    for (int n = 0; n < 4; ++n) acc[m][n] = f32x4{0.f, 0.f, 0.f, 0.f};

  int nkb = Kdim / 64;
  for (int kb = 0; kb < nkb; ++kb) {
#pragma unroll
    for (int i = 0; i < 4; ++i)
      gload_lds16(gA[i] + kb * 64, &As[i * 2048 + wv * 512]);
    {
      const float4* s = reinterpret_cast<const float4*>(wdp + kb * 64);
#pragma unroll
      for (int q = 0; q < 4; ++q)
        pack8(bsw[q], s[q * 2], s[q * 2 + 1]);
    }
    __syncthreads();
#pragma unroll
    for (int kk = 0; kk < 2; ++kk) {
      int soff = (((kk * 4 + (lane >> 4)) ^ (lane & 7)) << 3);
      bf16x8 a[4], b[4];
#pragma unroll
      for (int m = 0; m < 4; ++m)
        a[m] = lds_frag(&As[(wm * 64 + m * 16 + (lane & 15)) * 64 + soff]);
#pragma unroll
      for (int n = 0; n < 4; ++n)
        b[n] = lds_frag(&Bs[(wn * 64 + n * 16 + (lane & 15)) * 64 + soff]);
#pragma unroll
      for (int m = 0; m < 4; ++m)
#pragma unroll
        for (int n = 0; n < 4; ++n)
          acc[m][n] = mfma16(a[m], b[n], acc[m][n]);
    }
    __syncthreads();
  }

#pragma unroll
  for (int m = 0; m < 4; ++m) {
#pragma unroll
    for (int j = 0; j < 4; ++j) {
      int r = wm * 64 + m * 16 + (lane >> 4) * 4 + j;
      if (m0 + r < cnt) {
        int tok = 0; float coef = 1.f;
        if constexpr (SHARED) { tok = m0 + r; }
        else if constexpr (!YB) { tok = list[offE + m0 + r]; coef = cw[offE + m0 + r]; }
        else { coef = cw[offE + m0 + r]; }
#pragma unroll
        for (int n = 0; n < 4; ++n) {
          int col = n0 + wn * 64 + n * 16 + (lane & 15);
          float v = acc[m][n][j] * coef;
          if constexpr (SHARED) out[(size_t)tok * Hn + col] = v;
          else if constexpr (YB) yb[(size_t)(offE + m0 + r) * Hn + col] = f2bf(v);
          else atomicAdd(&out[(size_t)tok * Hn + col], v);
        }
      }
    }
  }
}

// ---------------- combine: out[t] += sum_k yb[rowOf[t,k]] ----------------
__global__ __launch_bounds__(256)
void combine_k(const unsigned short* __restrict__ yb, const int* __restrict__ rowOf,
               float* __restrict__ out) {
  int t = blockIdx.x;
  int c = threadIdx.x * 8;
  float* op = out + (size_t)t * Hn + c;
  float4 a0 = *reinterpret_cast<float4*>(op);
  float4 a1 = *reinterpret_cast<float4*>(op + 4);
#pragma unroll
  for (int k = 0; k < Kn; ++k) {
    int r = rowOf[t * Kn + k];
    u16x8 v = *reinterpret_cast<const u16x8*>(yb + (size_t)r * Hn + c);
    a0.x += bf2f(v[0]); a0.y += bf2f(v[1]); a0.z += bf2f(v[2]); a0.w += bf2f(v[3]);
    a1.x += bf2f(v[4]); a1.y += bf2f(v[5]); a1.z += bf2f(v[6]); a1.w += bf2f(v[7]);
  }
  *reinterpret_cast<float4*>(op) = a0;
  *reinterpret_cast<float4*>(op + 4) = a1;
}

extern "C" void kernel_launch(void* const* d_in, const int* in_sizes, int n_in,
                              void* d_out, int out_size, void* d_ws, size_t ws_size,
                              hipStream_t stream) {
  const float* x   = (const float*)d_in[0];
  const float* rg  = (const float*)d_in[1];
  const float* ru  = (const float*)d_in[2];
  const float* esc = (const float*)d_in[3];
  const float* ebi = (const float*)d_in[4];
  const float* Wg  = (const float*)d_in[5];
  const float* Wu  = (const float*)d_in[6];
  const float* Wd  = (const float*)d_in[7];
  const float* Sg  = (const float*)d_in[8];
  const float* Su  = (const float*)d_in[9];
  const float* Sd  = (const float*)d_in[10];
  float* out = (float*)d_out;

  char* ws = (char*)d_ws;
  const size_t sz_xb  = (size_t)Tn * Hn * 2;                    // 33.5 MB
  const size_t sz_hrt = (size_t)(Rn + 128) * In * 2;            // 92.6 MB
  const size_t sz_hsh = (size_t)(Tn + 128) * ISHn * 2;          // 46.9 MB
  const size_t sz_misc = 1 << 20;                               // 1 MB
  const size_t sz_yb  = (size_t)Rn * Hn * 2;                    // 134.2 MB

  unsigned short* xb  = (unsigned short*)(ws);
  unsigned short* hrt = (unsigned short*)(ws + sz_xb);
  unsigned short* hsh = (unsigned short*)(ws + sz_xb + sz_hrt);
  char* misc = ws + sz_xb + sz_hrt + sz_hsh;
  int*   counts = (int*)(misc);
  int*   cursor = (int*)(misc + 64);
  int*   off    = (int*)(misc + 128);
  int*   topk   = (int*)(misc + 256);
  float* wval   = (float*)(misc + 256 + 131072);
  int*   list   = (int*)(misc + 256 + 2 * 131072);
  float* cw     = (float*)(misc + 256 + 3 * 131072);
  int*   rowOf  = (int*)(misc + 256 + 4 * 131072);
  unsigned short* yb = (unsigned short*)(misc + sz_misc);

  const size_t need_yb = sz_xb + sz_hrt + sz_hsh + sz_misc + sz_yb;
  const bool use_yb = ws_size >= need_yb;

  zero_k<<<1, 32, 0, stream>>>(counts);  // counts[16]+cursor[16]
  cvt_x<<<2048, 256, 0, stream>>>(x, xb);
  router_k<<<2048, 256, 0, stream>>>(x, rg, ru, esc, ebi, counts, topk, wval);
  prefix_k<<<1, 64, 0, stream>>>(counts, off);
  build_k<<<Tn / 256, 256, 0, stream>>>(topk, wval, off, cursor, list, cw, rowOf);

  up_k<false><<<dim3(64, In / 64, En), 256, 0, stream>>>(xb, Wg, Wu, list, off, counts, hrt, In);
  up_k<true><<<dim3(Tn / 128, ISHn / 64, 1), 256, 0, stream>>>(xb, Sg, Su, nullptr, nullptr, nullptr, hsh, ISHn);
  // shared down writes out with plain stores (must precede routed accumulation)
  down_k<true, false><<<dim3(Tn / 128, Hn / 128, 1), 256, 0, stream>>>(
      hsh, Sd, nullptr, nullptr, nullptr, nullptr, out, nullptr, ISHn);
  if (use_yb) {
    down_k<false, true><<<dim3(64, Hn / 128, En), 256, 0, stream>>>(
        hrt, Wd, list, off, counts, cw, out, yb, In);
    combine_k<<<Tn, 256, 0, stream>>>(yb, rowOf, out);
  } else {
    down_k<false, false><<<dim3(64, Hn / 128, En), 256, 0, stream>>>(
        hrt, Wd, list, off, counts, cw, out, nullptr, In);
  }
}

// Round 3
// 1907.458 us; speedup vs baseline: 1.7608x; 1.7608x over previous
//
#include <hip/hip_runtime.h>
#include <hip/hip_bf16.h>
#include <cmath>

#define DEVI __device__ __forceinline__

constexpr int Hn   = 2048;   // hidden
constexpr int In   = 1408;   // per-expert intermediate
constexpr int En   = 16;     // routed experts
constexpr int Kn   = 4;      // top-k
constexpr int ISHn = 2816;   // shared intermediate
constexpr int Tn   = 8192;   // tokens (B*S)
constexpr int Rn   = Tn * Kn; // total routed rows = 32768

typedef __attribute__((ext_vector_type(4))) float f32x4;
typedef __attribute__((ext_vector_type(8))) __bf16 bf16x8;
typedef __attribute__((ext_vector_type(8))) unsigned short u16x8;

DEVI unsigned short f2bf(float f) {
  unsigned int u = __builtin_bit_cast(unsigned int, f);
  unsigned int r = (u + 0x7fffu + ((u >> 16) & 1u)) >> 16;
  return (unsigned short)r;
}
DEVI float bf2f(unsigned short h) {
  return __builtin_bit_cast(float, (unsigned int)h << 16);
}

DEVI f32x4 mfma16(bf16x8 a, bf16x8 b, f32x4 c) {
  return __builtin_amdgcn_mfma_f32_16x16x32_bf16(a, b, c, 0, 0, 0);
}

DEVI bf16x8 lds_frag(const unsigned short* p) {
  return __builtin_bit_cast(bf16x8, *reinterpret_cast<const u16x8*>(p));
}

DEVI void gload_lds16(const void* src, void* dst) {
  __builtin_amdgcn_global_load_lds(
      (const __attribute__((address_space(1))) void*)src,
      (__attribute__((address_space(3))) void*)dst, 16, 0, 0);
}

DEVI void pack8(unsigned short* dst, float4 a, float4 b) {
  u16x8 v;
  v[0] = f2bf(a.x); v[1] = f2bf(a.y); v[2] = f2bf(a.z); v[3] = f2bf(a.w);
  v[4] = f2bf(b.x); v[5] = f2bf(b.y); v[6] = f2bf(b.z); v[7] = f2bf(b.w);
  *reinterpret_cast<u16x8*>(dst) = v;
}

// ---------------- generic fp32 -> bf16 (vec8) ----------------
__global__ void cvt_w(const float* __restrict__ in, unsigned short* __restrict__ o, long n8) {
  long stride = (long)gridDim.x * blockDim.x;
  for (long v = blockIdx.x * (long)blockDim.x + threadIdx.x; v < n8; v += stride) {
    const float4* s = reinterpret_cast<const float4*>(in + v * 8);
    float4 a = s[0], b = s[1];
    u16x8 r;
    r[0] = f2bf(a.x); r[1] = f2bf(a.y); r[2] = f2bf(a.z); r[3] = f2bf(a.w);
    r[4] = f2bf(b.x); r[5] = f2bf(b.y); r[6] = f2bf(b.z); r[7] = f2bf(b.w);
    reinterpret_cast<u16x8*>(o)[v] = r;
  }
}

// ---------------- zero counts + cursor ----------------
__global__ void zero_k(int* p) { p[threadIdx.x] = 0; }

// ---------------- router: one wave per token, fp64 scoring ----------------
__global__ __launch_bounds__(256)
void router_k(const float* __restrict__ x, const float* __restrict__ rg,
              const float* __restrict__ ru, const float* __restrict__ esc,
              const float* __restrict__ ebi, int* __restrict__ counts,
              int* __restrict__ topk, float* __restrict__ wval) {
  int w = (blockIdx.x * blockDim.x + threadIdx.x) >> 6;
  int lane = threadIdx.x & 63;
  if (w >= Tn) return;
  const float* xr = x + (size_t)w * Hn;
  float xv[Hn / 64];
#pragma unroll
  for (int j = 0; j < Hn / 64; ++j) xv[j] = xr[lane + j * 64];

  double pr[En];
  double mx = -1e300;
#pragma unroll
  for (int e = 0; e < En; ++e) {
    const float* gr = rg + (size_t)e * Hn;
    const float* ur = ru + (size_t)e * Hn;
    double pg = 0.0, pu = 0.0;
#pragma unroll
    for (int j = 0; j < Hn / 64; ++j) {
      pg += (double)xv[j] * (double)gr[lane + j * 64];
      pu += (double)xv[j] * (double)ur[lane + j * 64];
    }
#pragma unroll
    for (int s = 32; s > 0; s >>= 1) {
      pg += __shfl_xor(pg, s);
      pu += __shfl_xor(pu, s);
    }
    double sg = pg / (1.0 + exp(-pg));     // silu
    double sc = fabs(pu * sg);
    pr[e] = sc;
    mx = fmax(mx, sc);
  }
  double den = 0.0;
#pragma unroll
  for (int e = 0; e < En; ++e) { pr[e] = exp(pr[e] - mx); den += pr[e]; }

  if (lane == 0) {
    double invden = 1.0 / den;
    unsigned chosen = 0;
    for (int k = 0; k < Kn; ++k) {
      double bv = -1e300; int best = 0;
#pragma unroll
      for (int e = 0; e < En; ++e) {
        double be = pr[e] * invden + (double)ebi[e];
        if (!((chosen >> e) & 1u) && be > bv) { bv = be; best = e; }
      }
      chosen |= 1u << best;
      topk[w * Kn + k] = best;
      double pbest = bv - (double)ebi[best];
      wval[w * Kn + k] = (float)(1.0 + pbest * (double)esc[best]);
      atomicAdd(&counts[best], 1);
    }
  }
}

// ---------------- prefix over expert counts ----------------
__global__ void prefix_k(const int* __restrict__ counts, int* __restrict__ off) {
  if (threadIdx.x == 0) {
    int a = 0;
    for (int e = 0; e < En; ++e) { off[e] = a; a += counts[e]; }
    off[En] = a;
  }
}

// ---------------- build per-expert token lists + token->row map ----------------
__global__ void build_k(const int* __restrict__ topk, const float* __restrict__ wval,
                        const int* __restrict__ off, int* __restrict__ cursor,
                        int* __restrict__ list, float* __restrict__ cw,
                        int* __restrict__ rowOf) {
  int t = blockIdx.x * blockDim.x + threadIdx.x;
  if (t >= Tn) return;
  for (int k = 0; k < Kn; ++k) {
    int e = topk[t * Kn + k];
    int pos = atomicAdd(&cursor[e], 1);
    int r = off[e] + pos;
    list[r] = t;
    cw[r] = wval[t * Kn + k];
    rowOf[t * Kn + k] = r;
  }
}

// ======================================================================
// NEW PATH: bf16 weights, 128x128-intensity tiles, fused silu epilogue
// ======================================================================

// up3: h = silu(A@Bg^T) * (A@Bu^T). Block computes 128 rows x 64 cols of h.
// Bs rows 0-63 = Bg rows n0..n0+63, rows 64-127 = Bu rows n0..n0+63.
// Fragment n=0,1 -> g, n=2,3 -> u of the SAME output columns (same thread).
template <bool GATHER>
__global__ __launch_bounds__(256, 2)
void up3_k(const unsigned short* __restrict__ xb,
           const unsigned short* __restrict__ Bg, const unsigned short* __restrict__ Bu,
           int Nhalf,
           const int* __restrict__ list, const int* __restrict__ off,
           const int* __restrict__ counts,
           unsigned short* __restrict__ hbuf) {
  int cnt, offE;
  const unsigned short *bg, *bu;
  if constexpr (GATHER) {
    int e = blockIdx.z;
    cnt = counts[e]; offE = off[e];
    size_t es = (size_t)Nhalf * Hn;
    bg = Bg + (size_t)e * es; bu = Bu + (size_t)e * es;
  } else { cnt = Tn; offE = 0; bg = Bg; bu = Bu; }
  int m0 = blockIdx.x * 128;
  if (m0 >= cnt) return;
  int n0 = blockIdx.y * 64;

  __shared__ alignas(16) unsigned short As[128 * 64];
  __shared__ alignas(16) unsigned short Bs[128 * 64];

  int tid = threadIdx.x, lane = tid & 63, wv = tid >> 6;
  int wm = wv >> 1, wn = wv & 1;

  const unsigned short* gA[4];
  const unsigned short* gB[4];
#pragma unroll
  for (int i = 0; i < 4; ++i) {
    int idx = i * 256 + tid;
    int row = idx >> 3, ch = idx & 7;
    int sch = ch ^ (row & 7);
    int rc = m0 + row; rc = rc < cnt ? rc : cnt - 1;
    int tok;
    if constexpr (GATHER) tok = list[offE + rc];
    else tok = rc;
    gA[i] = xb + (size_t)tok * Hn + sch * 8;
    const unsigned short* bb = (row < 64) ? (bg + (size_t)(n0 + row) * Hn)
                                          : (bu + (size_t)(n0 + row - 64) * Hn);
    gB[i] = bb + sch * 8;
  }

  // fragment LDS row offsets (elements)
  int aOff[4], bOff[4];
#pragma unroll
  for (int m = 0; m < 4; ++m) aOff[m] = (wm * 64 + m * 16 + (lane & 15)) * 64;
#pragma unroll
  for (int n = 0; n < 4; ++n)
    bOff[n] = ((n >> 1) * 64 + wn * 32 + (n & 1) * 16 + (lane & 15)) * 64;

  f32x4 acc[4][4];
#pragma unroll
  for (int m = 0; m < 4; ++m)
#pragma unroll
    for (int n = 0; n < 4; ++n) acc[m][n] = f32x4{0.f, 0.f, 0.f, 0.f};

  for (int kb = 0; kb < Hn / 64; ++kb) {
#pragma unroll
    for (int i = 0; i < 4; ++i)
      gload_lds16(gA[i] + kb * 64, &As[i * 2048 + wv * 512]);
#pragma unroll
    for (int i = 0; i < 4; ++i)
      gload_lds16(gB[i] + kb * 64, &Bs[i * 2048 + wv * 512]);
    __syncthreads();
#pragma unroll
    for (int kk = 0; kk < 2; ++kk) {
      int soff = (((kk * 4 + (lane >> 4)) ^ (lane & 7)) << 3);
      bf16x8 a[4], b[4];
#pragma unroll
      for (int m = 0; m < 4; ++m) a[m] = lds_frag(&As[aOff[m] + soff]);
#pragma unroll
      for (int n = 0; n < 4; ++n) b[n] = lds_frag(&Bs[bOff[n] + soff]);
#pragma unroll
      for (int m = 0; m < 4; ++m)
#pragma unroll
        for (int n = 0; n < 4; ++n)
          acc[m][n] = mfma16(a[m], b[n], acc[m][n]);
    }
    __syncthreads();
  }

#pragma unroll
  for (int m = 0; m < 4; ++m) {
#pragma unroll
    for (int j = 0; j < 4; ++j) {
      int r = wm * 64 + m * 16 + (lane >> 4) * 4 + j;
      if (m0 + r < cnt) {
#pragma unroll
        for (int n = 0; n < 2; ++n) {
          int col = n0 + wn * 32 + n * 16 + (lane & 15);
          float g = acc[m][n][j], u = acc[m][n + 2][j];
          float h = (g / (1.f + __expf(-g))) * u;
          hbuf[(size_t)(offE + m0 + r) * Nhalf + col] = f2bf(h);
        }
      }
    }
  }
}

// down3: C = h @ B^T (B bf16 [Hn][Kdim]). SHARED -> f32 stores to out;
// else bf16*coef stores to yb.
template <bool SHARED>
__global__ __launch_bounds__(256, 2)
void down3_k(const unsigned short* __restrict__ hbuf,
             const unsigned short* __restrict__ Bq, int Kdim,
             const int* __restrict__ off, const int* __restrict__ counts,
             const float* __restrict__ cw,
             float* __restrict__ out, unsigned short* __restrict__ yb) {
  int cnt, offE;
  const unsigned short* bq;
  if constexpr (SHARED) { cnt = Tn; offE = 0; bq = Bq; }
  else {
    int e = blockIdx.z;
    cnt = counts[e]; offE = off[e];
    bq = Bq + (size_t)e * Hn * Kdim;
  }
  int m0 = blockIdx.x * 128;
  if (m0 >= cnt) return;
  int n0 = blockIdx.y * 128;

  __shared__ alignas(16) unsigned short As[128 * 64];
  __shared__ alignas(16) unsigned short Bs[128 * 64];

  int tid = threadIdx.x, lane = tid & 63, wv = tid >> 6;
  int wm = wv >> 1, wn = wv & 1;

  const unsigned short* gA[4];
  const unsigned short* gB[4];
#pragma unroll
  for (int i = 0; i < 4; ++i) {
    int idx = i * 256 + tid;
    int row = idx >> 3, ch = idx & 7;
    int sch = ch ^ (row & 7);
    int rc = m0 + row; rc = rc < cnt ? rc : cnt - 1;
    gA[i] = hbuf + (size_t)(offE + rc) * Kdim + sch * 8;
    gB[i] = bq + (size_t)(n0 + row) * Kdim + sch * 8;
  }

  int aOff[4], bOff[4];
#pragma unroll
  for (int m = 0; m < 4; ++m) aOff[m] = (wm * 64 + m * 16 + (lane & 15)) * 64;
#pragma unroll
  for (int n = 0; n < 4; ++n) bOff[n] = (wn * 64 + n * 16 + (lane & 15)) * 64;

  f32x4 acc[4][4];
#pragma unroll
  for (int m = 0; m < 4; ++m)
#pragma unroll
    for (int n = 0; n < 4; ++n) acc[m][n] = f32x4{0.f, 0.f, 0.f, 0.f};

  int nkb = Kdim / 64;
  for (int kb = 0; kb < nkb; ++kb) {
#pragma unroll
    for (int i = 0; i < 4; ++i)
      gload_lds16(gA[i] + kb * 64, &As[i * 2048 + wv * 512]);
#pragma unroll
    for (int i = 0; i < 4; ++i)
      gload_lds16(gB[i] + kb * 64, &Bs[i * 2048 + wv * 512]);
    __syncthreads();
#pragma unroll
    for (int kk = 0; kk < 2; ++kk) {
      int soff = (((kk * 4 + (lane >> 4)) ^ (lane & 7)) << 3);
      bf16x8 a[4], b[4];
#pragma unroll
      for (int m = 0; m < 4; ++m) a[m] = lds_frag(&As[aOff[m] + soff]);
#pragma unroll
      for (int n = 0; n < 4; ++n) b[n] = lds_frag(&Bs[bOff[n] + soff]);
#pragma unroll
      for (int m = 0; m < 4; ++m)
#pragma unroll
        for (int n = 0; n < 4; ++n)
          acc[m][n] = mfma16(a[m], b[n], acc[m][n]);
    }
    __syncthreads();
  }

#pragma unroll
  for (int m = 0; m < 4; ++m) {
#pragma unroll
    for (int j = 0; j < 4; ++j) {
      int r = wm * 64 + m * 16 + (lane >> 4) * 4 + j;
      if (m0 + r < cnt) {
        float coef = 1.f;
        if constexpr (!SHARED) coef = cw[offE + m0 + r];
#pragma unroll
        for (int n = 0; n < 4; ++n) {
          int col = n0 + wn * 64 + n * 16 + (lane & 15);
          float v = acc[m][n][j] * coef;
          if constexpr (SHARED) out[(size_t)(m0 + r) * Hn + col] = v;
          else yb[(size_t)(offE + m0 + r) * Hn + col] = f2bf(v);
        }
      }
    }
  }
}

// ---------------- combine: out[t] += sum_k yb[rowOf[t,k]] ----------------
__global__ __launch_bounds__(256)
void combine_k(const unsigned short* __restrict__ yb, const int* __restrict__ rowOf,
               float* __restrict__ out) {
  int t = blockIdx.x;
  int c = threadIdx.x * 8;
  float* op = out + (size_t)t * Hn + c;
  float4 a0 = *reinterpret_cast<float4*>(op);
  float4 a1 = *reinterpret_cast<float4*>(op + 4);
#pragma unroll
  for (int k = 0; k < Kn; ++k) {
    int r = rowOf[t * Kn + k];
    u16x8 v = *reinterpret_cast<const u16x8*>(yb + (size_t)r * Hn + c);
    a0.x += bf2f(v[0]); a0.y += bf2f(v[1]); a0.z += bf2f(v[2]); a0.w += bf2f(v[3]);
    a1.x += bf2f(v[4]); a1.y += bf2f(v[5]); a1.z += bf2f(v[6]); a1.w += bf2f(v[7]);
  }
  *reinterpret_cast<float4*>(op) = a0;
  *reinterpret_cast<float4*>(op + 4) = a1;
}

// ======================================================================
// OLD PATH (round-2 kernels) — fallback when ws is too small for bf16 weights
// ======================================================================
__global__ void cvt_x_old(const float* __restrict__ x, unsigned short* __restrict__ xb) {
  constexpr int Nv = Tn * Hn / 4;
  int stride = gridDim.x * blockDim.x;
  for (int v = blockIdx.x * blockDim.x + threadIdx.x; v < Nv; v += stride) {
    float4 a = reinterpret_cast<const float4*>(x)[v];
    ushort4 o;
    o.x = f2bf(a.x); o.y = f2bf(a.y); o.z = f2bf(a.z); o.w = f2bf(a.w);
    reinterpret_cast<ushort4*>(xb)[v] = o;
  }
}

template <bool SHARED>
__global__ __launch_bounds__(256, 2)
void up_k(const unsigned short* __restrict__ xb,
          const float* __restrict__ Wgp, const float* __restrict__ Wup,
          const int* __restrict__ list, const int* __restrict__ off,
          const int* __restrict__ counts,
          unsigned short* __restrict__ hbuf, int Ncols) {
  int cnt, offE;
  const float *wg, *wu;
  if constexpr (SHARED) { cnt = Tn; offE = 0; wg = Wgp; wu = Wup; }
  else {
    int e = blockIdx.z;
    cnt = counts[e]; offE = off[e];
    wg = Wgp + (size_t)e * In * Hn; wu = Wup + (size_t)e * In * Hn;
  }
  int m0 = blockIdx.x * 128;
  if (m0 >= cnt) return;
  int n0 = blockIdx.y * 64;

  __shared__ alignas(16) unsigned short As[128 * 64];
  __shared__ alignas(16) unsigned short Bg[64 * 64];
  __shared__ alignas(16) unsigned short Bu[64 * 64];

  int tid = threadIdx.x, lane = tid & 63, wv = tid >> 6;
  int wm = wv >> 1, wn = wv & 1;

  const unsigned short* gA[4];
#pragma unroll
  for (int i = 0; i < 4; ++i) {
    int idx = i * 256 + tid;
    int row = idx >> 3, ch = idx & 7;
    int rc = m0 + row; rc = rc < cnt ? rc : cnt - 1;
    int tok;
    if constexpr (SHARED) tok = m0 + row;
    else tok = list[offE + rc];
    gA[i] = xb + (size_t)tok * Hn + ch * 8;
  }
  int brow = tid >> 2, bq = tid & 3;
  const float* wgp = wg + (size_t)(n0 + brow) * Hn + bq * 16;
  const float* wup = wu + (size_t)(n0 + brow) * Hn + bq * 16;
  unsigned short* bgs = &Bg[brow * 64 + bq * 16];
  unsigned short* bus = &Bu[brow * 64 + bq * 16];

  f32x4 accg[4][2], accu[4][2];
#pragma unroll
  for (int m = 0; m < 4; ++m)
#pragma unroll
    for (int n = 0; n < 2; ++n) {
      accg[m][n] = f32x4{0.f, 0.f, 0.f, 0.f};
      accu[m][n] = f32x4{0.f, 0.f, 0.f, 0.f};
    }

  for (int kb = 0; kb < Hn / 64; ++kb) {
#pragma unroll
    for (int i = 0; i < 4; ++i)
      gload_lds16(gA[i] + kb * 64, &As[i * 2048 + wv * 512]);
    {
      const float4* s = reinterpret_cast<const float4*>(wgp + kb * 64);
      pack8(bgs, s[0], s[1]);
      pack8(bgs + 8, s[2], s[3]);
      const float4* s2 = reinterpret_cast<const float4*>(wup + kb * 64);
      pack8(bus, s2[0], s2[1]);
      pack8(bus + 8, s2[2], s2[3]);
    }
    __syncthreads();
#pragma unroll
    for (int kk = 0; kk < 2; ++kk) {
      int klo = kk * 32 + (lane >> 4) * 8;
      bf16x8 a[4], bg2[2], bu2[2];
#pragma unroll
      for (int m = 0; m < 4; ++m)
        a[m] = lds_frag(&As[(wm * 64 + m * 16 + (lane & 15)) * 64 + klo]);
#pragma unroll
      for (int n = 0; n < 2; ++n) {
        bg2[n] = lds_frag(&Bg[(wn * 32 + n * 16 + (lane & 15)) * 64 + klo]);
        bu2[n] = lds_frag(&Bu[(wn * 32 + n * 16 + (lane & 15)) * 64 + klo]);
      }
#pragma unroll
      for (int m = 0; m < 4; ++m)
#pragma unroll
        for (int n = 0; n < 2; ++n) {
          accg[m][n] = mfma16(a[m], bg2[n], accg[m][n]);
          accu[m][n] = mfma16(a[m], bu2[n], accu[m][n]);
        }
    }
    __syncthreads();
  }

#pragma unroll
  for (int m = 0; m < 4; ++m) {
#pragma unroll
    for (int j = 0; j < 4; ++j) {
      int r = wm * 64 + m * 16 + (lane >> 4) * 4 + j;
      if (m0 + r < cnt) {
#pragma unroll
        for (int n = 0; n < 2; ++n) {
          int col = n0 + wn * 32 + n * 16 + (lane & 15);
          float g = accg[m][n][j], u = accu[m][n][j];
          float h = (g / (1.f + __expf(-g))) * u;
          hbuf[(size_t)(offE + m0 + r) * Ncols + col] = f2bf(h);
        }
      }
    }
  }
}

template <bool SHARED, bool YB>
__global__ __launch_bounds__(256, 2)
void down_k(const unsigned short* __restrict__ hbuf,
            const float* __restrict__ Wdp,
            const int* __restrict__ list, const int* __restrict__ off,
            const int* __restrict__ counts, const float* __restrict__ cw,
            float* __restrict__ out, unsigned short* __restrict__ yb, int Kdim) {
  int cnt, offE;
  const float* wd;
  if constexpr (SHARED) { cnt = Tn; offE = 0; wd = Wdp; }
  else {
    int e = blockIdx.z;
    cnt = counts[e]; offE = off[e];
    wd = Wdp + (size_t)e * Hn * In;
  }
  int m0 = blockIdx.x * 128;
  if (m0 >= cnt) return;
  int n0 = blockIdx.y * 128;

  __shared__ alignas(16) unsigned short As[128 * 64];
  __shared__ alignas(16) unsigned short Bs[128 * 64];

  int tid = threadIdx.x, lane = tid & 63, wv = tid >> 6;
  int wm = wv >> 1, wn = wv & 1;

  const unsigned short* gA[4];
#pragma unroll
  for (int i = 0; i < 4; ++i) {
    int idx = i * 256 + tid;
    int row = idx >> 3, ch = idx & 7;
    int rc = m0 + row; rc = rc < cnt ? rc : cnt - 1;
    gA[i] = hbuf + (size_t)(offE + rc) * Kdim + ch * 8;
  }
  int brow = tid >> 1, bh = tid & 1;
  const float* wdp = wd + (size_t)(n0 + brow) * Kdim + bh * 32;
  unsigned short* bsp = &Bs[brow * 64 + bh * 32];

  f32x4 acc[4][4];
#pragma unroll
  for (int m = 0; m < 4; ++m)
#pragma unroll
    for (int n = 0; n < 4; ++n) acc[m][n] = f32x4{0.f, 0.f, 0.f, 0.f};

  int nkb = Kdim / 64;
  for (int kb = 0; kb < nkb; ++kb) {
#pragma unroll
    for (int i = 0; i < 4; ++i)
      gload_lds16(gA[i] + kb * 64, &As[i * 2048 + wv * 512]);
    {
      const float4* s = reinterpret_cast<const float4*>(wdp + kb * 64);
#pragma unroll
      for (int q = 0; q < 4; ++q)
        pack8(bsp + q * 8, s[q * 2], s[q * 2 + 1]);
    }
    __syncthreads();
#pragma unroll
    for (int kk = 0; kk < 2; ++kk) {
      int klo = kk * 32 + (lane >> 4) * 8;
      bf16x8 a[4], b[4];
#pragma unroll
      for (int m = 0; m < 4; ++m)
        a[m] = lds_frag(&As[(wm * 64 + m * 16 + (lane & 15)) * 64 + klo]);
#pragma unroll
      for (int n = 0; n < 4; ++n)
        b[n] = lds_frag(&Bs[(wn * 64 + n * 16 + (lane & 15)) * 64 + klo]);
#pragma unroll
      for (int m = 0; m < 4; ++m)
#pragma unroll
        for (int n = 0; n < 4; ++n)
          acc[m][n] = mfma16(a[m], b[n], acc[m][n]);
    }
    __syncthreads();
  }

#pragma unroll
  for (int m = 0; m < 4; ++m) {
#pragma unroll
    for (int j = 0; j < 4; ++j) {
      int r = wm * 64 + m * 16 + (lane >> 4) * 4 + j;
      if (m0 + r < cnt) {
        int tok = 0; float coef = 1.f;
        if constexpr (SHARED) { tok = m0 + r; }
        else if constexpr (!YB) { tok = list[offE + m0 + r]; coef = cw[offE + m0 + r]; }
        else { coef = cw[offE + m0 + r]; }
#pragma unroll
        for (int n = 0; n < 4; ++n) {
          int col = n0 + wn * 64 + n * 16 + (lane & 15);
          float v = acc[m][n][j] * coef;
          if constexpr (SHARED) out[(size_t)tok * Hn + col] = v;
          else if constexpr (YB) yb[(size_t)(offE + m0 + r) * Hn + col] = f2bf(v);
          else atomicAdd(&out[(size_t)tok * Hn + col], v);
        }
      }
    }
  }
}

// ======================================================================
extern "C" void kernel_launch(void* const* d_in, const int* in_sizes, int n_in,
                              void* d_out, int out_size, void* d_ws, size_t ws_size,
                              hipStream_t stream) {
  const float* x   = (const float*)d_in[0];
  const float* rg  = (const float*)d_in[1];
  const float* ru  = (const float*)d_in[2];
  const float* esc = (const float*)d_in[3];
  const float* ebi = (const float*)d_in[4];
  const float* Wg  = (const float*)d_in[5];
  const float* Wu  = (const float*)d_in[6];
  const float* Wd  = (const float*)d_in[7];
  const float* Sg  = (const float*)d_in[8];
  const float* Su  = (const float*)d_in[9];
  const float* Sd  = (const float*)d_in[10];
  float* out = (float*)d_out;

  char* ws = (char*)d_ws;

  // ---- new-path layout ----
  const size_t sz_xb  = (size_t)Tn * Hn * 2;           //  33.6 MB
  const size_t sz_wgu = (size_t)En * In * Hn * 2;      //  92.3 MB (each of wg,wu,wd)
  const size_t sz_sgu = (size_t)ISHn * Hn * 2;         //  11.5 MB (each of sg,su,sd)
  const size_t sz_hrt = (size_t)Rn * In * 2;           //  92.3 MB
  const size_t sz_hsh = (size_t)Tn * ISHn * 2;         //  46.1 MB
  const size_t sz_misc = 1 << 20;

  size_t o = 0;
  auto take = [&](size_t b) { size_t r = o; o += (b + 255) & ~(size_t)255; return r; };
  size_t o_xb  = take(sz_xb);
  size_t o_wg  = take(sz_wgu);
  size_t o_wu  = take(sz_wgu);
  size_t o_wd  = take(sz_wgu);
  size_t o_sg  = take(sz_sgu);
  size_t o_su  = take(sz_sgu);
  size_t o_sd  = take(sz_sgu);
  size_t o_hrt = take(sz_hrt);
  size_t o_hsh = take(sz_hsh);
  size_t o_mi  = take(sz_misc);
  const size_t need_new = o;

  if (ws_size >= need_new) {
    unsigned short* xb  = (unsigned short*)(ws + o_xb);
    unsigned short* wgq = (unsigned short*)(ws + o_wg);
    unsigned short* wuq = (unsigned short*)(ws + o_wu);
    unsigned short* wdq = (unsigned short*)(ws + o_wd);
    unsigned short* sgq = (unsigned short*)(ws + o_sg);
    unsigned short* suq = (unsigned short*)(ws + o_su);
    unsigned short* sdq = (unsigned short*)(ws + o_sd);
    unsigned short* hrt = (unsigned short*)(ws + o_hrt);
    unsigned short* hsh = (unsigned short*)(ws + o_hsh);
    char* misc = ws + o_mi;
    int*   counts = (int*)(misc);
    int*   cursor = (int*)(misc + 64);
    int*   off    = (int*)(misc + 128);
    int*   topk   = (int*)(misc + 256);
    float* wval   = (float*)(misc + 256 + 131072);
    int*   list   = (int*)(misc + 256 + 2 * 131072);
    float* cw     = (float*)(misc + 256 + 3 * 131072);
    int*   rowOf  = (int*)(misc + 256 + 4 * 131072);
    // yb aliases wg+wu bf16 region (dead after up kernels): 134.2 MB <= 184.5 MB
    unsigned short* yb = wgq;

    zero_k<<<1, 32, 0, stream>>>(counts);
    cvt_x_old<<<2048, 256, 0, stream>>>(x, xb);
    router_k<<<2048, 256, 0, stream>>>(x, rg, ru, esc, ebi, counts, topk, wval);
    prefix_k<<<1, 64, 0, stream>>>(counts, off);
    build_k<<<Tn / 256, 256, 0, stream>>>(topk, wval, off, cursor, list, cw, rowOf);

    const long n8_w = (long)En * In * Hn / 8;
    const long n8_s = (long)ISHn * Hn / 8;
    cvt_w<<<2048, 256, 0, stream>>>(Wg, wgq, n8_w);
    cvt_w<<<2048, 256, 0, stream>>>(Wu, wuq, n8_w);
    cvt_w<<<2048, 256, 0, stream>>>(Wd, wdq, n8_w);
    cvt_w<<<1024, 256, 0, stream>>>(Sg, sgq, n8_s);
    cvt_w<<<1024, 256, 0, stream>>>(Su, suq, n8_s);
    cvt_w<<<1024, 256, 0, stream>>>(Sd, sdq, n8_s);

    // shared up: M=8192, Nhalf=2816 -> grid (64, 44)
    up3_k<false><<<dim3(Tn / 128, ISHn / 64, 1), 256, 0, stream>>>(
        xb, sgq, suq, ISHn, nullptr, nullptr, nullptr, hsh);
    // routed up: Nhalf=1408 -> grid (64, 22, 16)
    up3_k<true><<<dim3(64, In / 64, En), 256, 0, stream>>>(
        xb, wgq, wuq, In, list, off, counts, hrt);
    // shared down: writes out plain f32 (before combine)
    down3_k<true><<<dim3(Tn / 128, Hn / 128, 1), 256, 0, stream>>>(
        hsh, sdq, ISHn, nullptr, nullptr, nullptr, out, nullptr);
    // routed down: writes yb bf16 (aliases dead wg/wu region)
    down3_k<false><<<dim3(64, Hn / 128, En), 256, 0, stream>>>(
        hrt, wdq, In, off, counts, cw, nullptr, yb);
    combine_k<<<Tn, 256, 0, stream>>>(yb, rowOf, out);
    return;
  }

  // ---- old fallback layout (round-2 path) ----
  const size_t f_xb  = (size_t)Tn * Hn * 2;
  const size_t f_hrt = (size_t)(Rn + 128) * In * 2;
  const size_t f_hsh = (size_t)(Tn + 128) * ISHn * 2;
  const size_t f_misc = 1 << 20;
  const size_t f_yb  = (size_t)Rn * Hn * 2;

  unsigned short* xb  = (unsigned short*)(ws);
  unsigned short* hrt = (unsigned short*)(ws + f_xb);
  unsigned short* hsh = (unsigned short*)(ws + f_xb + f_hrt);
  char* misc = ws + f_xb + f_hrt + f_hsh;
  int*   counts = (int*)(misc);
  int*   cursor = (int*)(misc + 64);
  int*   off    = (int*)(misc + 128);
  int*   topk   = (int*)(misc + 256);
  float* wval   = (float*)(misc + 256 + 131072);
  int*   list   = (int*)(misc + 256 + 2 * 131072);
  float* cw     = (float*)(misc + 256 + 3 * 131072);
  int*   rowOf  = (int*)(misc + 256 + 4 * 131072);
  unsigned short* yb = (unsigned short*)(misc + f_misc);

  const size_t need_yb = f_xb + f_hrt + f_hsh + f_misc + f_yb;
  const bool use_yb = ws_size >= need_yb;

  zero_k<<<1, 32, 0, stream>>>(counts);
  cvt_x_old<<<2048, 256, 0, stream>>>(x, xb);
  router_k<<<2048, 256, 0, stream>>>(x, rg, ru, esc, ebi, counts, topk, wval);
  prefix_k<<<1, 64, 0, stream>>>(counts, off);
  build_k<<<Tn / 256, 256, 0, stream>>>(topk, wval, off, cursor, list, cw, rowOf);

  up_k<false><<<dim3(64, In / 64, En), 256, 0, stream>>>(xb, Wg, Wu, list, off, counts, hrt, In);
  up_k<true><<<dim3(Tn / 128, ISHn / 64, 1), 256, 0, stream>>>(xb, Sg, Su, nullptr, nullptr, nullptr, hsh, ISHn);
  down_k<true, false><<<dim3(Tn / 128, Hn / 128, 1), 256, 0, stream>>>(
      hsh, Sd, nullptr, nullptr, nullptr, nullptr, out, nullptr, ISHn);
  if (use_yb) {
    down_k<false, true><<<dim3(64, Hn / 128, En), 256, 0, stream>>>(
        hrt, Wd, list, off, counts, cw, out, yb, In);
    combine_k<<<Tn, 256, 0, stream>>>(yb, rowOf, out);
  } else {
    down_k<false, false><<<dim3(64, Hn / 128, En), 256, 0, stream>>>(
        hrt, Wd, list, off, counts, cw, out, nullptr, In);
  }
}